// Round 9
// baseline (95.555 us; speedup 1.0000x reference)
//
#include <hip/hip_runtime.h>
#include <hip/hip_fp16.h>
#include <math.h>

#define NATOM   32
#define NSP     4
#define NCLS    10
#define NSHFR   16
#define NSHFA   4
#define NSHFZ   8
#define FEAT_ANG (NSHFA * NSHFZ)            // 32
#define OUT_PER_ATOM (NSP * NSHFR + NCLS * FEAT_ANG)  // 384
#define MAXP    465                          // 31*30/2 worst-case pairs

#define RCR_F 5.2f
#define RCA_F 3.5f
#define PI_F  3.14159265358979323846f

__device__ __forceinline__ int tri(int n) { return (n * (n - 1)) >> 1; }

// one packed pair record: x=0.5*cos, y=0.5*sin, z=half2(e0,e1), w=half2(e2,e3)
template <bool FAST>
__device__ __forceinline__ float pair_term(float4 r, int p, float ct, float st, float zt)
{
    const float u = fmaf(r.x, ct, fmaf(r.y, st, 0.5f));
    float f1;
    if (FAST) {
        const float u2 = u * u, u4 = u2 * u2, u8 = u4 * u4, u16 = u8 * u8;
        f1 = u16 * u16;                       // u^32, u in [0,1]
    } else {
        f1 = __powf(fmaxf(u, 0.f), zt);
    }
    const unsigned ez = (p & 2) ? __float_as_uint(r.w) : __float_as_uint(r.z);
    const __half2 hh = *reinterpret_cast<const __half2*>(&ez);
    const float e = (p & 1) ? __high2float(hh) : __low2float(hh);
    return f1 * e;
}

// depth-1 software-prefetched segment scan: ds_read for pp+1 issues before
// the pow/fma chain for pp, hiding ~64-cyc LDS latency behind compute
template <bool FAST>
__device__ __forceinline__ void angular_accum(
    const float4* __restrict__ pc, int s0, int e0, int p,
    float ct, float st, float zt, float& acc)
{
    if (s0 >= e0) return;
    float4 cur = pc[s0];
    const int last = e0 - 1;
    for (int pp = s0; pp < e0; ++pp) {
        const int nx = (pp < last) ? pp + 1 : last;
        const float4 nxt = pc[nx];
        acc += pair_term<FAST>(cur, p, ct, st, zt);
        cur = nxt;
    }
}

__global__ __launch_bounds__(64) void aev_kernel(
    const float* __restrict__ coords,   // (B, 32, 3)
    const float* __restrict__ etaR,     // (1,)
    const float* __restrict__ shfR,     // (16,)
    const float* __restrict__ etaA,     // (1,)
    const float* __restrict__ zeta,     // (1,)
    const float* __restrict__ shfA,     // (4,)
    const float* __restrict__ shfZ,     // (8,)
    const int*   __restrict__ species,  // (B, 32)
    float* __restrict__ out)            // (B, 32, 384)
{
    const int atom = blockIdx.x;        // b*32 + i
    const int b    = atom >> 5;
    const int i    = atom & 31;
    const int tid  = threadIdx.x;       // 0..63, single wave

    __shared__ float sco[NATOM * 3];                    // staged coords
    __shared__ __align__(16) float4 srad[NATOM];        // (d, fcR, sp, 0) - broadcast reads
    __shared__ float nvx[NATOM], nvy[NATOM], nvz[NATOM];// sorted SoA (conflict-free gathers)
    __shared__ float nd[NATOM], nfa[NATOM];
    __shared__ int   s_off[NCLS + 1];                   // class segment starts
    __shared__ __align__(16) float4 pc[MAXP];           // packed pair records

    // ---- stage coords (coalesced) + species loads ----
    for (int t = tid; t < NATOM * 3; t += 64) sco[t] = coords[b * (NATOM * 3) + t];
    int spj = -1, spi = -1;
    if (tid < NATOM) {
        spj = species[b * NATOM + tid];
        spi = species[b * NATOM + i];
    }
    __syncthreads();

    // ---- phase 1: per-neighbor precompute (lanes 0..31), sorted compaction ----
    bool  act = false;
    int   sp  = 0;
    float vx = 0.f, vy = 0.f, vz = 0.f, d = 0.f, fcA = 0.f;
    if (tid < NATOM) {
        const int j = tid;
        const float cx = sco[i * 3 + 0], cy = sco[i * 3 + 1], cz = sco[i * 3 + 2];
        vx = sco[j * 3 + 0] - cx;
        vy = sco[j * 3 + 1] - cy;
        vz = sco[j * 3 + 2] - cz;
        const float d2 = vx * vx + vy * vy + vz * vz;
        d = sqrtf(d2 > 0.f ? d2 : 1.f);
        const bool ok = (j != i) && (spj >= 0) && (spi >= 0);
        fcA = (ok && d <= RCA_F) ? (0.5f * __cosf(d * (PI_F / RCA_F)) + 0.5f) : 0.f;
        const float fcR = (ok && d <= RCR_F) ? (0.5f * __cosf(d * (PI_F / RCR_F)) + 0.5f) : 0.f;
        sp = spj < 0 ? 0 : (spj > (NSP - 1) ? (NSP - 1) : spj);
        srad[j] = make_float4(d, fcR, (float)sp, 0.f);
        act = fcA > 0.f;
    }

    // species ballots (whole wave; hi lanes act=false)
    const unsigned long long m0 = __ballot(act && sp == 0);
    const unsigned long long m1 = __ballot(act && sp == 1);
    const unsigned long long m2 = __ballot(act && sp == 2);
    const unsigned long long m3 = __ballot(act && sp == 3);
    const int n0 = (int)__popcll(m0), n1 = (int)__popcll(m1);
    const int n2 = (int)__popcll(m2), n3 = (int)__popcll(m3);
    const int B1 = n0, B2 = n0 + n1, B3 = n0 + n1 + n2;
    const int nn = B3 + n3;

    if (act) {
        const unsigned long long lt = (1ull << tid) - 1ull;
        int pos;
        if      (sp == 0) pos =      (int)__popcll(m0 & lt);
        else if (sp == 1) pos = B1 + (int)__popcll(m1 & lt);
        else if (sp == 2) pos = B2 + (int)__popcll(m2 & lt);
        else              pos = B3 + (int)__popcll(m3 & lt);
        nvx[pos] = vx; nvy[pos] = vy; nvz[pos] = vz;
        nd[pos] = d; nfa[pos] = fcA;
    }

    // class counts from species counts, offsets into LDS table
    const int c0 = tri(n0), c1 = n0 * n1, c2 = n0 * n2, c3 = n0 * n3;
    const int c4 = tri(n1), c5 = n1 * n2, c6 = n1 * n3;
    const int c7 = tri(n2), c8 = n2 * n3, c9 = tri(n3);
    const int np = c0 + c1 + c2 + c3 + c4 + c5 + c6 + c7 + c8 + c9;
    {
        int v = 0;
        v += (0 < tid) ? c0 : 0;  v += (1 < tid) ? c1 : 0;
        v += (2 < tid) ? c2 : 0;  v += (3 < tid) ? c3 : 0;
        v += (4 < tid) ? c4 : 0;  v += (5 < tid) ? c5 : 0;
        v += (6 < tid) ? c6 : 0;  v += (7 < tid) ? c7 : 0;
        v += (8 < tid) ? c8 : 0;  v += (9 < tid) ? c9 : 0;
        if (tid <= NCLS) s_off[tid] = v;     // s_off[10] == np
    }
    __syncthreads();

    const long obase = (long)atom * OUT_PER_ATOM;

    // ---- phase 2: radial, flat. lane = (s = tid>>4, r = tid&15) ----
    {
        const int s  = tid >> 4;
        const int r  = tid & 15;
        const float sf  = (float)s;
        const float shf = shfR[r];
        const float eta = etaR[0];
        float acc = 0.f;
#pragma unroll 4
        for (int j = 0; j < NATOM; ++j) {
            const float4 rd = srad[j];           // broadcast read (free)
            const float dd = rd.x - shf;
            const float v  = __expf(-eta * dd * dd) * rd.y;
            acc += (rd.z == sf) ? v : 0.f;
        }
        out[obase + tid] = 0.25f * acc;          // layout: s*16 + r == tid
    }

    // ---- phase 3: enumerate sorted neighbor pairs, deterministic placement ----
    const float eA  = etaA[0];
    const float sa0 = shfA[0], sa1 = shfA[1], sa2 = shfA[2], sa3 = shfA[3];
    for (int base = 0; base < np; base += 64) {
        const int p = base + tid;
        if (p < np) {
            // decode p -> (a, bb), a < bb over nn sorted neighbors
            const int tnn = 2 * nn - 1;
            int a = (int)(((float)tnn - sqrtf((float)(tnn * tnn - 8 * p))) * 0.5f);
            if (a < 0) a = 0;
            int Sa = a * (nn - 1) - tri(a);
            if (Sa > p) { --a; Sa = a * (nn - 1) - tri(a); }
            else {
                const int San = (a + 1) * (nn - 1) - tri(a + 1);
                if (San <= p) { ++a; Sa = San; }
            }
            const int bb = a + 1 + (p - Sa);
            // species via segment boundaries (sa <= sb since sorted)
            const int sa = (a  >= B1) + (a  >= B2) + (a  >= B3);
            const int sb = (bb >= B1) + (bb >= B2) + (bb >= B3);
            const int cls = sa * NSP - tri(sa) + (sb - sa);
            const int Bs  = (sa == 0) ? 0 : ((sa == 1) ? B1 : ((sa == 2) ? B2 : B3));
            const int Bt  = (sb == 0) ? 0 : ((sb == 1) ? B1 : ((sb == 2) ? B2 : B3));
            const int ns_ = (sa == 0) ? n0 : ((sa == 1) ? n1 : ((sa == 2) ? n2 : n3));
            const int nt_ = (sb == 0) ? n0 : ((sb == 1) ? n1 : ((sb == 2) ? n2 : n3));
            int lidx;
            if (sa == sb) {
                const int aa = a - Bs, bb2 = bb - Bs;
                lidx = aa * (ns_ - 1) - tri(aa) + (bb2 - aa - 1);
            } else {
                lidx = (a - Bs) * nt_ + (bb - Bt);
            }
            const int pos = s_off[cls] + lidx;
            // geometry + exp factors (scalar SoA gathers, conflict-free)
            const float da = nd[a], db = nd[bb];
            const float dot = nvx[a] * nvx[bb] + nvy[a] * nvy[bb] + nvz[a] * nvz[bb];
            const float cv = 0.95f * dot * __builtin_amdgcn_rcpf(fmaxf(da * db, 1e-10f));
            const float sv = __builtin_amdgcn_sqrtf(fmaxf(1.f - cv * cv, 0.f));
            const float dm = 0.5f * (da + db);
            const float fac = 2.f * nfa[a] * nfa[bb];
            const float d0 = dm - sa0, d1 = dm - sa1, d2 = dm - sa2, d3 = dm - sa3;
            const float e0 = fac * __expf(-eA * d0 * d0);
            const float e1 = fac * __expf(-eA * d1 * d1);
            const float e2 = fac * __expf(-eA * d2 * d2);
            const float e3 = fac * __expf(-eA * d3 * d3);
            const __half2 h01 = __floats2half2_rn(e0, e1);
            const __half2 h23 = __floats2half2_rn(e2, e3);
            pc[pos] = make_float4(0.5f * cv, 0.5f * sv,
                                  __uint_as_float(*reinterpret_cast<const unsigned*>(&h01)),
                                  __uint_as_float(*reinterpret_cast<const unsigned*>(&h23)));
        }
    }
    __syncthreads();

    // ---- phase 4: angular. halves own even/odd classes, prefetched b128 reads ----
    {
        const int f = tid & 31;
        const int p = f >> 3;        // ShfA index
        const int t = f & 7;         // ShfZ index
        const int half = tid >> 5;
        float st, ct;
        __sincosf(shfZ[t], &st, &ct);
        const float zt = zeta[0];
        float* oang = out + obase + NSP * NSHFR;

        if (zt == 32.0f) {
#pragma unroll
            for (int qi = 0; qi < NCLS / 2; ++qi) {
                const int q = qi * 2 + half;
                float acc = 0.f;
                angular_accum<true>(pc, s_off[q], s_off[q + 1], p, ct, st, zt, acc);
                oang[q * FEAT_ANG + f] = acc;
            }
        } else {
#pragma unroll
            for (int qi = 0; qi < NCLS / 2; ++qi) {
                const int q = qi * 2 + half;
                float acc = 0.f;
                angular_accum<false>(pc, s_off[q], s_off[q + 1], p, ct, st, zt, acc);
                oang[q * FEAT_ANG + f] = acc;
            }
        }
    }
}

extern "C" void kernel_launch(void* const* d_in, const int* in_sizes, int n_in,
                              void* d_out, int out_size, void* d_ws, size_t ws_size,
                              hipStream_t stream) {
    const float* coords  = (const float*)d_in[0];
    const float* etaR    = (const float*)d_in[1];
    const float* shfR    = (const float*)d_in[2];
    const float* etaA    = (const float*)d_in[3];
    const float* zeta    = (const float*)d_in[4];
    const float* shfA    = (const float*)d_in[5];
    const float* shfZ    = (const float*)d_in[6];
    const int*   species = (const int*)d_in[7];
    float* out = (float*)d_out;

    const int B = in_sizes[0] / (NATOM * 3);
    aev_kernel<<<B * NATOM, 64, 0, stream>>>(coords, etaR, shfR, etaA, zeta,
                                             shfA, shfZ, species, out);
}

// Round 10
// 86.423 us; speedup vs baseline: 1.1057x; 1.1057x over previous
//
#include <hip/hip_runtime.h>
#include <hip/hip_fp16.h>
#include <math.h>

#define NATOM   32
#define NSP     4
#define NCLS    10
#define NSHFR   16
#define NSHFA   4
#define NSHFZ   8
#define FEAT_ANG (NSHFA * NSHFZ)            // 32
#define OUT_PER_ATOM (NSP * NSHFR + NCLS * FEAT_ANG)  // 384
#define MAXP    465                          // 31*30/2 worst-case pairs

#define RCR_F 5.2f
#define RCA_F 3.5f
#define PI_F  3.14159265358979323846f

__device__ __forceinline__ int tri(int n) { return (n * (n - 1)) >> 1; }

// angular accumulation over one class segment; FAST => zeta == 32 (5 squarings)
template <bool FAST>
__device__ __forceinline__ void angular_accum(
    const float2* __restrict__ pc_cs, const __half* __restrict__ pc_eh,
    int s0, int e0, int p, float ct, float st, float zt, float& acc)
{
#pragma unroll 2
    for (int pp = s0; pp < e0; ++pp) {
        const float2 cs = pc_cs[pp];
        const float  ee = __half2float(pc_eh[pp * 4 + p]);
        // u = 0.5 + 0.5*cos(ang - ShfZ[t]);  cs holds (0.5*cos, 0.5*sin)
        const float u = fmaf(cs.x, ct, fmaf(cs.y, st, 0.5f));
        float f1;
        if (FAST) {
            const float u2 = u * u, u4 = u2 * u2, u8 = u4 * u4, u16 = u8 * u8;
            f1 = u16 * u16;                       // u^32, u in [0,1]
        } else {
            f1 = __powf(fmaxf(u, 0.f), zt);
        }
        acc = fmaf(f1, ee, acc);
    }
}

__global__ __launch_bounds__(64) void aev_kernel(
    const float* __restrict__ coords,   // (B, 32, 3)
    const float* __restrict__ etaR,     // (1,)
    const float* __restrict__ shfR,     // (16,)
    const float* __restrict__ etaA,     // (1,)
    const float* __restrict__ zeta,     // (1,)
    const float* __restrict__ shfA,     // (4,)
    const float* __restrict__ shfZ,     // (8,)
    const int*   __restrict__ species,  // (B, 32)
    float* __restrict__ out)            // (B, 32, 384)
{
    const int atom = blockIdx.x;        // b*32 + i
    const int b    = atom >> 5;
    const int i    = atom & 31;
    const int tid  = threadIdx.x;       // 0..63, single wave

    __shared__ float sco[NATOM * 3];                  // staged coords
    __shared__ float sd_o[NATOM], sfcR_o[NATOM];      // orig order (radial)
    __shared__ int   ssp_o[NATOM];
    __shared__ float nvx[NATOM], nvy[NATOM], nvz[NATOM];  // species-sorted
    __shared__ float nd[NATOM], nfa[NATOM];               // neighbor data
    __shared__ int   s_off[NCLS + 1];                 // class segment starts
    __shared__ float2 pc_cs[MAXP];                    // (0.5*cos, 0.5*sin)
    __shared__ __align__(8) __half pc_eh[MAXP * 4];   // fac*exp, p=0..3

    // ---- stage coords (coalesced) + issue species loads early ----
    for (int t = tid; t < NATOM * 3; t += 64) sco[t] = coords[b * (NATOM * 3) + t];
    int spj = -1, spi = -1;
    if (tid < NATOM) {
        spj = species[b * NATOM + tid];
        spi = species[b * NATOM + i];
    }
    __syncthreads();

    // ---- phase 1: per-neighbor precompute (lanes 0..31), sorted compaction ----
    bool  act = false;
    int   sp  = 0;
    float vx = 0.f, vy = 0.f, vz = 0.f, d = 0.f, fcA = 0.f;
    if (tid < NATOM) {
        const int j = tid;
        const float cx = sco[i * 3 + 0], cy = sco[i * 3 + 1], cz = sco[i * 3 + 2];
        vx = sco[j * 3 + 0] - cx;
        vy = sco[j * 3 + 1] - cy;
        vz = sco[j * 3 + 2] - cz;
        const float d2 = vx * vx + vy * vy + vz * vz;
        d = sqrtf(d2 > 0.f ? d2 : 1.f);
        const bool ok = (j != i) && (spj >= 0) && (spi >= 0);
        fcA = (ok && d <= RCA_F) ? (0.5f * __cosf(d * (PI_F / RCA_F)) + 0.5f) : 0.f;
        const float fcR = (ok && d <= RCR_F) ? (0.5f * __cosf(d * (PI_F / RCR_F)) + 0.5f) : 0.f;
        sp = spj < 0 ? 0 : (spj > (NSP - 1) ? (NSP - 1) : spj);
        sd_o[j] = d; sfcR_o[j] = fcR; ssp_o[j] = sp;
        act = fcA > 0.f;
    }

    // species ballots (whole wave; hi lanes act=false)
    const unsigned long long m0 = __ballot(act && sp == 0);
    const unsigned long long m1 = __ballot(act && sp == 1);
    const unsigned long long m2 = __ballot(act && sp == 2);
    const unsigned long long m3 = __ballot(act && sp == 3);
    const int n0 = (int)__popcll(m0), n1 = (int)__popcll(m1);
    const int n2 = (int)__popcll(m2), n3 = (int)__popcll(m3);
    const int B1 = n0, B2 = n0 + n1, B3 = n0 + n1 + n2;
    const int nn = B3 + n3;

    if (act) {
        const unsigned long long lt = (1ull << tid) - 1ull;
        int pos;
        if      (sp == 0) pos =      (int)__popcll(m0 & lt);
        else if (sp == 1) pos = B1 + (int)__popcll(m1 & lt);
        else if (sp == 2) pos = B2 + (int)__popcll(m2 & lt);
        else              pos = B3 + (int)__popcll(m3 & lt);
        nvx[pos] = vx; nvy[pos] = vy; nvz[pos] = vz;
        nd[pos] = d; nfa[pos] = fcA;
    }

    // class counts from species counts (uniform), offsets into LDS table
    const int c0 = tri(n0), c1 = n0 * n1, c2 = n0 * n2, c3 = n0 * n3;
    const int c4 = tri(n1), c5 = n1 * n2, c6 = n1 * n3;
    const int c7 = tri(n2), c8 = n2 * n3, c9 = tri(n3);
    const int np = c0 + c1 + c2 + c3 + c4 + c5 + c6 + c7 + c8 + c9;
    {
        int v = 0;
        v += (0 < tid) ? c0 : 0;  v += (1 < tid) ? c1 : 0;
        v += (2 < tid) ? c2 : 0;  v += (3 < tid) ? c3 : 0;
        v += (4 < tid) ? c4 : 0;  v += (5 < tid) ? c5 : 0;
        v += (6 < tid) ? c6 : 0;  v += (7 < tid) ? c7 : 0;
        v += (8 < tid) ? c8 : 0;  v += (9 < tid) ? c9 : 0;
        if (tid <= NCLS) s_off[tid] = v;     // s_off[10] == np
    }
    __syncthreads();

    const long obase = (long)atom * OUT_PER_ATOM;

    // ---- phase 2: radial. thread = (r = tid&15, jg = tid>>4) ----
    {
        const int r  = tid & 15;
        const int jg = tid >> 4;
        const float shf = shfR[r];
        const float eta = etaR[0];
        float a0 = 0.f, a1 = 0.f, a2 = 0.f, a3 = 0.f;
        for (int j = jg; j < NATOM; j += 4) {
            const float fc = sfcR_o[j];
            if (fc > 0.f) {
                const float dd = sd_o[j] - shf;
                const float v = 0.25f * __expf(-eta * dd * dd) * fc;
                const int s = ssp_o[j];
                a0 += (s == 0) ? v : 0.f;
                a1 += (s == 1) ? v : 0.f;
                a2 += (s == 2) ? v : 0.f;
                a3 += (s == 3) ? v : 0.f;
            }
        }
        a0 += __shfl_xor(a0, 16); a0 += __shfl_xor(a0, 32);
        a1 += __shfl_xor(a1, 16); a1 += __shfl_xor(a1, 32);
        a2 += __shfl_xor(a2, 16); a2 += __shfl_xor(a2, 32);
        a3 += __shfl_xor(a3, 16); a3 += __shfl_xor(a3, 32);
        if (tid < 16) {
            out[obase + 0 * NSHFR + r] = a0;
            out[obase + 1 * NSHFR + r] = a1;
            out[obase + 2 * NSHFR + r] = a2;
            out[obase + 3 * NSHFR + r] = a3;
        }
    }

    // ---- phase 3: enumerate sorted neighbor pairs, deterministic placement ----
    const float eA  = etaA[0];
    const float sa0 = shfA[0], sa1 = shfA[1], sa2 = shfA[2], sa3 = shfA[3];
    for (int base = 0; base < np; base += 64) {
        const int p = base + tid;
        if (p < np) {
            // decode p -> (a, bb), a < bb over nn sorted neighbors
            const int tnn = 2 * nn - 1;
            int a = (int)(((float)tnn - sqrtf((float)(tnn * tnn - 8 * p))) * 0.5f);
            if (a < 0) a = 0;
            int Sa = a * (nn - 1) - tri(a);
            if (Sa > p) { --a; Sa = a * (nn - 1) - tri(a); }
            else {
                const int San = (a + 1) * (nn - 1) - tri(a + 1);
                if (San <= p) { ++a; Sa = San; }
            }
            const int bb = a + 1 + (p - Sa);
            // species via segment boundaries (sa <= sb since sorted)
            const int sa = (a  >= B1) + (a  >= B2) + (a  >= B3);
            const int sb = (bb >= B1) + (bb >= B2) + (bb >= B3);
            const int cls = sa * NSP - tri(sa) + (sb - sa);
            const int Bs  = (sa == 0) ? 0 : ((sa == 1) ? B1 : ((sa == 2) ? B2 : B3));
            const int Bt  = (sb == 0) ? 0 : ((sb == 1) ? B1 : ((sb == 2) ? B2 : B3));
            const int ns_ = (sa == 0) ? n0 : ((sa == 1) ? n1 : ((sa == 2) ? n2 : n3));
            const int nt_ = (sb == 0) ? n0 : ((sb == 1) ? n1 : ((sb == 2) ? n2 : n3));
            int lidx;
            if (sa == sb) {
                const int aa = a - Bs, bb2 = bb - Bs;
                lidx = aa * (ns_ - 1) - tri(aa) + (bb2 - aa - 1);
            } else {
                lidx = (a - Bs) * nt_ + (bb - Bt);
            }
            const int pos = s_off[cls] + lidx;
            // geometry + exp factors (scalar SoA gathers, conflict-free)
            const float da = nd[a], db = nd[bb];
            const float dot = nvx[a] * nvx[bb] + nvy[a] * nvy[bb] + nvz[a] * nvz[bb];
            const float cv = 0.95f * dot * __builtin_amdgcn_rcpf(fmaxf(da * db, 1e-10f));
            const float sv = __builtin_amdgcn_sqrtf(fmaxf(1.f - cv * cv, 0.f));
            const float dm = 0.5f * (da + db);
            const float fac = 2.f * nfa[a] * nfa[bb];
            const float d0 = dm - sa0, d1 = dm - sa1, d2 = dm - sa2, d3 = dm - sa3;
            const float e0 = fac * __expf(-eA * d0 * d0);
            const float e1 = fac * __expf(-eA * d1 * d1);
            const float e2 = fac * __expf(-eA * d2 * d2);
            const float e3 = fac * __expf(-eA * d3 * d3);
            pc_cs[pos] = make_float2(0.5f * cv, 0.5f * sv);
            __half2* dst = reinterpret_cast<__half2*>(pc_eh + pos * 4);
            dst[0] = __floats2half2_rn(e0, e1);
            dst[1] = __floats2half2_rn(e2, e3);
        }
    }
    __syncthreads();

    // ---- phase 4: angular. halves own even/odd classes, lockstep qi loop ----
    {
        const int f = tid & 31;
        const int p = f >> 3;        // ShfA index
        const int t = f & 7;         // ShfZ index
        const int half = tid >> 5;
        float st, ct;
        __sincosf(shfZ[t], &st, &ct);
        const float zt = zeta[0];
        float* oang = out + obase + NSP * NSHFR;

        if (zt == 32.0f) {
#pragma unroll
            for (int qi = 0; qi < NCLS / 2; ++qi) {
                const int q = qi * 2 + half;
                const int s0 = s_off[q], e0 = s_off[q + 1];
                float acc = 0.f;
                angular_accum<true>(pc_cs, pc_eh, s0, e0, p, ct, st, zt, acc);
                oang[q * FEAT_ANG + f] = acc;
            }
        } else {
#pragma unroll
            for (int qi = 0; qi < NCLS / 2; ++qi) {
                const int q = qi * 2 + half;
                const int s0 = s_off[q], e0 = s_off[q + 1];
                float acc = 0.f;
                angular_accum<false>(pc_cs, pc_eh, s0, e0, p, ct, st, zt, acc);
                oang[q * FEAT_ANG + f] = acc;
            }
        }
    }
}

extern "C" void kernel_launch(void* const* d_in, const int* in_sizes, int n_in,
                              void* d_out, int out_size, void* d_ws, size_t ws_size,
                              hipStream_t stream) {
    const float* coords  = (const float*)d_in[0];
    const float* etaR    = (const float*)d_in[1];
    const float* shfR    = (const float*)d_in[2];
    const float* etaA    = (const float*)d_in[3];
    const float* zeta    = (const float*)d_in[4];
    const float* shfA    = (const float*)d_in[5];
    const float* shfZ    = (const float*)d_in[6];
    const int*   species = (const int*)d_in[7];
    float* out = (float*)d_out;

    const int B = in_sizes[0] / (NATOM * 3);
    aev_kernel<<<B * NATOM, 64, 0, stream>>>(coords, etaR, shfR, etaA, zeta,
                                             shfA, shfZ, species, out);
}